// Round 1
// baseline (417.151 us; speedup 1.0000x reference)
//
#include <hip/hip_runtime.h>
#include <hip/hip_bf16.h>

#define EPSF 1e-5f

typedef int v4i __attribute__((ext_vector_type(4)));
typedef short v8s __attribute__((ext_vector_type(8)));

static constexpr int BB = 4, TT = 1024, DD = 2048, HH = 8192;
static constexpr int MROWS = BB * TT;                   // 4096
static constexpr long long WCOUNT = (long long)DD * HH; // 2^24 per weight

// ---------------------------------------------------------------- helpers

__device__ __forceinline__ void async_copy16(const void* g, void* l) {
  __builtin_amdgcn_global_load_lds(
      (const __attribute__((address_space(1))) unsigned int*)g,
      (__attribute__((address_space(3))) unsigned int*)l,
      16, 0, 0);
}

// counted vmcnt + bare barrier in ONE asm (memory clobber: no VMEM/DS op may
// cross; avoids __syncthreads()'s forced vmcnt(0) drain — the m97-class stall).
template <int N>
__device__ __forceinline__ void wait_bar() {
  if constexpr (N == 8)
    asm volatile("s_waitcnt vmcnt(8)\n\ts_barrier" ::: "memory");
  else if constexpr (N == 6)
    asm volatile("s_waitcnt vmcnt(6)\n\ts_barrier" ::: "memory");
  else if constexpr (N == 4)
    asm volatile("s_waitcnt vmcnt(4)\n\ts_barrier" ::: "memory");
  else if constexpr (N == 3)
    asm volatile("s_waitcnt vmcnt(3)\n\ts_barrier" ::: "memory");
  else
    asm volatile("s_waitcnt vmcnt(0)\n\ts_barrier" ::: "memory");
}

__device__ __forceinline__ int pack4(float a, float b, float c, float d,
                                     float scale, float lo, float hi) {
  int ia = (int)fminf(fmaxf(rintf(a * scale), lo), hi);
  int ib = (int)fminf(fmaxf(rintf(b * scale), lo), hi);
  int ic = (int)fminf(fmaxf(rintf(c * scale), lo), hi);
  int id = (int)fminf(fmaxf(rintf(d * scale), lo), hi);
  return (ia & 0xff) | ((ib & 0xff) << 8) | ((ic & 0xff) << 16) | ((id & 0xff) << 24);
}

__device__ __forceinline__ float abs4(float4 v) {
  return fmaxf(fmaxf(fabsf(v.x), fabsf(v.y)), fmaxf(fabsf(v.z), fabsf(v.w)));
}

__device__ __forceinline__ int blockMaxI256(int v) {
  #pragma unroll
  for (int off = 32; off; off >>= 1) v = max(v, __shfl_down(v, off, 64));
  __shared__ int sm[4];
  int lane = threadIdx.x & 63, wv = threadIdx.x >> 6;
  if (lane == 0) sm[wv] = v;
  __syncthreads();
  return max(max(sm[0], sm[1]), max(sm[2], sm[3]));
}

// XCD-aware tile swizzle: id%8 class (heuristic XCD) owns a contiguous patch.
__device__ __forceinline__ void swizzle_tiles(int& mt, int& nt) {
  int Mt = gridDim.y, Nt = gridDim.x;
  int id = blockIdx.y * Nt + blockIdx.x;
  int c = id & 7, k = id >> 3;
  int pm = (Mt >= Nt) ? 4 : 2;
  int PM = Mt / pm, PN = Nt / (8 / pm);
  int pr = c % pm, pc = c / pm;
  mt = pr * PM + (k % PM);
  nt = pc * PN + (k / PM);
}

// ---------------------------------------------------------------- |w| partial sums

__global__ __launch_bounds__(256) void abs_sum_kernel(
    const float* __restrict__ w1, const float* __restrict__ w2,
    float* __restrict__ partials) {
  const int y = blockIdx.y, bid = blockIdx.x, t = threadIdx.x;
  const int lane = t & 63, wv = t >> 6;
  const float4* w4 = (const float4*)(y ? w2 : w1);
  const long long base = (long long)bid * 2048;
  float4 u[8];
  #pragma unroll
  for (int k = 0; k < 8; k++) u[k] = w4[base + t + k * 256];
  float s = 0.f;
  #pragma unroll
  for (int k = 0; k < 8; k++)
    s += fabsf(u[k].x) + fabsf(u[k].y) + fabsf(u[k].z) + fabsf(u[k].w);
  #pragma unroll
  for (int off = 32; off; off >>= 1) s += __shfl_down(s, off, 64);
  __shared__ float sm[4];
  if (lane == 0) sm[wv] = s;
  __syncthreads();
  if (t == 0) partials[y * 2048 + bid] = sm[0] + sm[1] + sm[2] + sm[3];
}

// ---------------------------------------------------------------- ternary quant

__global__ __launch_bounds__(256) void quant_w_kernel(
    const float* __restrict__ w1, const float* __restrict__ w2,
    const float* __restrict__ partials, float* __restrict__ meanw,
    signed char* __restrict__ q1, signed char* __restrict__ q2) {
  const int y = blockIdx.y, bid = blockIdx.x, t = threadIdx.x;
  const int lane = t & 63, wv = t >> 6;

  double d = 0.0;
  #pragma unroll
  for (int j = 0; j < 8; j++) d += (double)partials[y * 2048 + t + j * 256];
  #pragma unroll
  for (int off = 32; off; off >>= 1) d += __shfl_down(d, off, 64);
  __shared__ double smd[4];
  if (lane == 0) smd[wv] = d;
  __syncthreads();
  double sum = smd[0] + smd[1] + smd[2] + smd[3];
  float mean = fmaxf((float)(sum * (1.0 / (double)WCOUNT)), EPSF);
  if (bid == 0 && t == 0) meanw[y] = mean;
  float sc = 1.0f / mean;

  const float4* w4 = (const float4*)(y ? w2 : w1);
  int* q4 = (int*)(y ? q2 : q1);
  const long long base = (long long)bid * 2048;
  float4 u[8];
  #pragma unroll
  for (int k = 0; k < 8; k++) u[k] = w4[base + t + k * 256];
  #pragma unroll
  for (int k = 0; k < 8; k++)
    q4[base + t + k * 256] = pack4(u[k].x, u[k].y, u[k].z, u[k].w, sc, -1.f, 1.f);
}

// ---------------------------------------------------------------- act quant x (wave = row)

__global__ __launch_bounds__(256) void quant_x_kernel(
    const float* __restrict__ x, signed char* __restrict__ xq,
    float* __restrict__ ascale) {
  int lane = threadIdx.x & 63, wv = threadIdx.x >> 6;
  int row = blockIdx.x * 4 + wv;
  const float4* xr = (const float4*)(x + (size_t)row * DD);
  float4 v[8];
  #pragma unroll
  for (int j = 0; j < 8; j++) v[j] = xr[lane + j * 64];
  float m = 0.f;
  #pragma unroll
  for (int j = 0; j < 8; j++) m = fmaxf(m, abs4(v[j]));
  #pragma unroll
  for (int off = 32; off; off >>= 1) m = fmaxf(m, __shfl_down(m, off, 64));
  m = __shfl(m, 0, 64);
  float am = fmaxf(m, EPSF);
  float scale = 127.0f / am;
  int* out = (int*)(xq + (size_t)row * DD);
  #pragma unroll
  for (int j = 0; j < 8; j++)
    out[lane + j * 64] = pack4(v[j].x, v[j].y, v[j].z, v[j].w, scale, -128.f, 127.f);
  if (lane == 0) ascale[row] = am / 127.0f;
}

// ---------------------------------------------------------------- act quant h (int16 in)

__global__ __launch_bounds__(256) void quant_h_kernel(
    const short* __restrict__ h, signed char* __restrict__ hq,
    float* __restrict__ a2, const float* __restrict__ a1,
    const float* __restrict__ meanw) {
  int row = blockIdx.x;
  int t = threadIdx.x;
  const v8s* hr = (const v8s*)(h + (size_t)row * HH);
  v8s v[4];
  #pragma unroll
  for (int i = 0; i < 4; i++) v[i] = hr[t + i * 256];
  int mx = 0;
  #pragma unroll
  for (int i = 0; i < 4; i++)
    #pragma unroll
    for (int j = 0; j < 8; j++) mx = max(mx, (int)v[i][j]);
  int bmx = blockMaxI256(mx);
  float f = a1[row] * meanw[0];      // per-row dequant factor (exact ref path)
  float maxh = (float)bmx * f;       // == max_j fl(r_j*f): fl monotone, f>=0
  float am = fmaxf(maxh, EPSF);
  float scale = 127.0f / am;
  int* out = (int*)(hq + (size_t)row * HH);
  #pragma unroll
  for (int i = 0; i < 4; i++) {
    out[(t + i * 256) * 2] =
        pack4((float)v[i][0] * f, (float)v[i][1] * f, (float)v[i][2] * f,
              (float)v[i][3] * f, scale, -128.f, 127.f);
    out[(t + i * 256) * 2 + 1] =
        pack4((float)v[i][4] * f, (float)v[i][5] * f, (float)v[i][6] * f,
              (float)v[i][7] * f, scale, -128.f, 127.f);
  }
  if (t == 0) a2[row] = am / 127.0f;
}

// ---------------------------------------------------------------- int8 GEMM, ring-4 counted-vmcnt
// C[M][N] = sum_k A[M][K]*B[N][K].  512 thr / 8 waves (WM x WN), tile BM x BN,
// K-step 64.  4-slot LDS ring: iter t computes slot t&3 while staging tile t+3
// into slot (t+3)&3 — written slot is disjoint from every readable slot, so a
// bare s_barrier per K-step suffices and vmcnt stays counted (2 tiles = 2L
// loads in flight; NEVER drained to 0 in the main loop).  Slot freed at the
// barrier ending iter t-1 (all ds_reads drained into regs by the MFMA lgkmcnt
// dependency) before tile t+3's stage is issued in iter t.
// LDS layout: row-major 64B rows; 16B chunk slot s of row r holds source
// chunk s ^ ((r>>1)&3) (involution, applied on the pre-swizzled global source
// per the global_load_lds linear-dest rule).  Frag read lanes then cover all
// 8 bank-slots 2-way (free), same structure as the verified CH=8 scheme.
// MODE 1: relu -> int16 store (exact). MODE 0: scaled fp32 store.

template <int MODE, int BM, int BN, int WM, int WN>
__global__ __launch_bounds__(512, 2) void gemm_i8_ring(
    const signed char* __restrict__ A, const signed char* __restrict__ B,
    void* __restrict__ Cout, const float* __restrict__ ascale,
    const float* __restrict__ wmean_p, int M, int N, int K) {
  static_assert(WM * WN == 8, "8 waves");
  constexpr int WTM = BM / WM, WTN = BN / WN;    // wave output tile
  constexpr int MI = WTM / 16, NJ = WTN / 16;    // 16x16 frags per wave
  constexpr int SA_W = BM / 128;                 // 1024B segments per wave (A)
  constexpr int SB_W = BN / 128;                 // (B)
  constexpr int L = SA_W + SB_W;                 // loads/thread/K-tile
  constexpr int ABYTES = BM * 64, BBYTES = BN * 64;

  __shared__ __align__(16) signed char As[4][ABYTES];
  __shared__ __align__(16) signed char Bs[4][BBYTES];

  const int t = threadIdx.x;
  const int lane = t & 63, wv = t >> 6;
  const int wm = wv / WN, wn = wv % WN;
  const int q = lane >> 4;

  int mt, nt;
  swizzle_tiles(mt, nt);
  const int m0 = mt * BM, n0 = nt * BN;

  // staging: per-lane pre-swizzled global source, linear LDS dest
  const signed char* aSrcP[SA_W];
  int aDst[SA_W];
  #pragma unroll
  for (int i = 0; i < SA_W; i++) {
    int seg = wv * SA_W + i;
    int r = seg * 16 + (lane >> 2);
    int c = (lane & 3) ^ ((r >> 1) & 3);
    aSrcP[i] = A + (size_t)(m0 + r) * K + c * 16;
    aDst[i] = seg * 1024;
  }
  const signed char* bSrcP[SB_W];
  int bDst[SB_W];
  #pragma unroll
  for (int i = 0; i < SB_W; i++) {
    int seg = wv * SB_W + i;
    int r = seg * 16 + (lane >> 2);
    int c = (lane & 3) ^ ((r >> 1) & 3);
    bSrcP[i] = B + (size_t)(n0 + r) * K + c * 16;
    bDst[i] = seg * 1024;
  }

  // fragment LDS byte offsets (constant per thread)
  int aOff[MI], bOff[NJ];
  #pragma unroll
  for (int i = 0; i < MI; i++) {
    int r = wm * WTM + i * 16 + (lane & 15);
    aOff[i] = r * 64 + ((q ^ ((r >> 1) & 3)) << 4);
  }
  #pragma unroll
  for (int j = 0; j < NJ; j++) {
    int r = wn * WTN + j * 16 + (lane & 15);
    bOff[j] = r * 64 + ((q ^ ((r >> 1) & 3)) << 4);
  }

  v4i acc[MI][NJ];
  #pragma unroll
  for (int i = 0; i < MI; i++)
    #pragma unroll
    for (int j = 0; j < NJ; j++) {
      v4i z = {0, 0, 0, 0};
      acc[i][j] = z;
    }

  auto stage = [&](int kt, int sl) {
    #pragma unroll
    for (int i = 0; i < SA_W; i++)
      async_copy16(aSrcP[i] + (size_t)kt * 64, &As[sl][aDst[i]]);
    #pragma unroll
    for (int i = 0; i < SB_W; i++)
      async_copy16(bSrcP[i] + (size_t)kt * 64, &Bs[sl][bDst[i]]);
  };
  auto compute = [&](int sl) {
    const signed char* as_ = As[sl];
    const signed char* bs_ = Bs[sl];
    v4i af[MI], bf[NJ];
    #pragma unroll
    for (int i = 0; i < MI; i++) af[i] = *(const v4i*)(as_ + aOff[i]);
    #pragma unroll
    for (int j = 0; j < NJ; j++) bf[j] = *(const v4i*)(bs_ + bOff[j]);
    __builtin_amdgcn_s_setprio(1);
    #pragma unroll
    for (int i = 0; i < MI; i++)
      #pragma unroll
      for (int j = 0; j < NJ; j++)
        acc[i][j] =
            __builtin_amdgcn_mfma_i32_16x16x64_i8(af[i], bf[j], acc[i][j], 0, 0, 0);
    __builtin_amdgcn_s_setprio(0);
  };

  const int NTK = K >> 6;
  // prologue: 3 tiles in flight; wait leaves 2L outstanding (tiles 1,2)
  stage(0, 0);
  stage(1, 1);
  stage(2, 2);
  wait_bar<2 * L>();
  // steady state: compute t, stage t+3; wait leaves tiles t+2,t+3 in flight
  for (int kt = 0; kt < NTK - 3; ++kt) {
    stage(kt + 3, (kt + 3) & 3);
    compute(kt & 3);
    wait_bar<2 * L>();
  }
  // epilogue drain: 2L -> L -> 0
  compute((NTK - 3) & 3);
  wait_bar<L>();
  compute((NTK - 2) & 3);
  wait_bar<0>();
  compute((NTK - 1) & 3);

  if constexpr (MODE == 1) {
    short* C = (short*)Cout;
    #pragma unroll
    for (int i = 0; i < MI; i++) {
      int mBase = m0 + wm * WTM + i * 16 + q * 4;
      #pragma unroll
      for (int e = 0; e < 4; e++) {
        #pragma unroll
        for (int j = 0; j < NJ; j++) {
          int n = n0 + wn * WTN + j * 16 + (lane & 15);
          int r = acc[i][j][e];
          r = r < 0 ? 0 : (r > 32767 ? 32767 : r);
          C[(size_t)(mBase + e) * N + n] = (short)r;
        }
      }
    }
  } else {
    float* C = (float*)Cout;
    float wmean = wmean_p[0];
    #pragma unroll
    for (int i = 0; i < MI; i++) {
      int mBase = m0 + wm * WTM + i * 16 + q * 4;
      #pragma unroll
      for (int e = 0; e < 4; e++) {
        float f = ascale[mBase + e] * wmean;
        #pragma unroll
        for (int j = 0; j < NJ; j++) {
          int n = n0 + wn * WTN + j * 16 + (lane & 15);
          C[(size_t)(mBase + e) * N + n] = (float)acc[i][j][e] * f;
        }
      }
    }
  }
}

// ---------------------------------------------------------------- launch

extern "C" void kernel_launch(void* const* d_in, const int* in_sizes, int n_in,
                              void* d_out, int out_size, void* d_ws, size_t ws_size,
                              hipStream_t stream) {
  const float* x  = (const float*)d_in[0];
  const float* w1 = (const float*)d_in[1];
  const float* w2 = (const float*)d_in[2];
  float* out = (float*)d_out;

  char* ws = (char*)d_ws;
  float* meanw = (float*)ws;                                // 2 f32
  float* partials = (float*)(ws + 1024);                    // 4096 f32 (16 KB)
  float* a1 = (float*)(ws + 20480);                         // 4096 f32
  float* a2 = (float*)(ws + 40960);                         // 4096 f32
  signed char* w1q = (signed char*)(ws + 65536);            // 16 MB
  signed char* w2q = w1q + (size_t)WCOUNT;                  // 16 MB
  signed char* xq  = w2q + (size_t)WCOUNT;                  // 8 MB
  signed char* hq  = xq + (size_t)MROWS * DD;               // 32 MB
  short* h16 = (short*)(hq + (size_t)MROWS * HH);           // 64 MB int16

  abs_sum_kernel<<<dim3(2048, 2), 256, 0, stream>>>(w1, w2, partials);
  quant_w_kernel<<<dim3(2048, 2), 256, 0, stream>>>(w1, w2, partials, meanw, w1q, w2q);
  quant_x_kernel<<<MROWS / 4, 256, 0, stream>>>(x, xq, a1);
  // GEMM1: M=4096, N=8192, K=2048 — 256x256 tile, waves 2x4, relu->int16
  gemm_i8_ring<1, 256, 256, 2, 4><<<dim3(HH / 256, MROWS / 256), 512, 0, stream>>>(
      xq, w1q, h16, nullptr, meanw, MROWS, HH, DD);
  quant_h_kernel<<<MROWS, 256, 0, stream>>>(h16, hq, a2, a1, meanw);
  // GEMM2: M=4096, N=2048, K=8192 — 256x128 tile, waves 4x2, scaled fp32
  gemm_i8_ring<0, 256, 128, 4, 2><<<dim3(DD / 128, MROWS / 256), 512, 0, stream>>>(
      hq, w2q, out, a2, &meanw[1], MROWS, DD, HH);
}

// Round 2
// 374.672 us; speedup vs baseline: 1.1134x; 1.1134x over previous
//
#include <hip/hip_runtime.h>
#include <hip/hip_bf16.h>

#define EPSF 1e-5f

typedef int v4i __attribute__((ext_vector_type(4)));
typedef short v8s __attribute__((ext_vector_type(8)));

static constexpr int BB = 4, TT = 1024, DD = 2048, HH = 8192;
static constexpr int MROWS = BB * TT;                   // 4096
static constexpr long long WCOUNT = (long long)DD * HH; // 2^24 per weight

// ---------------------------------------------------------------- helpers

__device__ __forceinline__ void async_copy16(const void* g, void* l) {
  __builtin_amdgcn_global_load_lds(
      (const __attribute__((address_space(1))) unsigned int*)g,
      (__attribute__((address_space(3))) unsigned int*)l,
      16, 0, 0);
}

__device__ __forceinline__ int pack4(float a, float b, float c, float d,
                                     float scale, float lo, float hi) {
  int ia = (int)fminf(fmaxf(rintf(a * scale), lo), hi);
  int ib = (int)fminf(fmaxf(rintf(b * scale), lo), hi);
  int ic = (int)fminf(fmaxf(rintf(c * scale), lo), hi);
  int id = (int)fminf(fmaxf(rintf(d * scale), lo), hi);
  return (ia & 0xff) | ((ib & 0xff) << 8) | ((ic & 0xff) << 16) | ((id & 0xff) << 24);
}

__device__ __forceinline__ float abs4(float4 v) {
  return fmaxf(fmaxf(fabsf(v.x), fabsf(v.y)), fmaxf(fabsf(v.z), fabsf(v.w)));
}

__device__ __forceinline__ int blockMaxI256(int v) {
  #pragma unroll
  for (int off = 32; off; off >>= 1) v = max(v, __shfl_down(v, off, 64));
  __shared__ int sm[4];
  int lane = threadIdx.x & 63, wv = threadIdx.x >> 6;
  if (lane == 0) sm[wv] = v;
  __syncthreads();
  return max(max(sm[0], sm[1]), max(sm[2], sm[3]));
}

// XCD-aware tile swizzle: id%8 class (heuristic XCD) owns a contiguous patch.
__device__ __forceinline__ void swizzle_tiles(int& mt, int& nt) {
  int Mt = gridDim.y, Nt = gridDim.x;
  int id = blockIdx.y * Nt + blockIdx.x;
  int c = id & 7, k = id >> 3;
  int pm = (Mt >= Nt) ? 4 : 2;
  int PM = Mt / pm, PN = Nt / (8 / pm);
  int pr = c % pm, pc = c / pm;
  mt = pr * PM + (k % PM);
  nt = pc * PN + (k / PM);
}

// ---------------------------------------------------------------- |w| partial sums

__global__ __launch_bounds__(256) void abs_sum_kernel(
    const float* __restrict__ w1, const float* __restrict__ w2,
    float* __restrict__ partials) {
  const int y = blockIdx.y, bid = blockIdx.x, t = threadIdx.x;
  const int lane = t & 63, wv = t >> 6;
  const float4* w4 = (const float4*)(y ? w2 : w1);
  const long long base = (long long)bid * 2048;
  float4 u[8];
  #pragma unroll
  for (int k = 0; k < 8; k++) u[k] = w4[base + t + k * 256];
  float s = 0.f;
  #pragma unroll
  for (int k = 0; k < 8; k++)
    s += fabsf(u[k].x) + fabsf(u[k].y) + fabsf(u[k].z) + fabsf(u[k].w);
  #pragma unroll
  for (int off = 32; off; off >>= 1) s += __shfl_down(s, off, 64);
  __shared__ float sm[4];
  if (lane == 0) sm[wv] = s;
  __syncthreads();
  if (t == 0) partials[y * 2048 + bid] = sm[0] + sm[1] + sm[2] + sm[3];
}

// ---------------------------------------------------------------- ternary quant

__global__ __launch_bounds__(256) void quant_w_kernel(
    const float* __restrict__ w1, const float* __restrict__ w2,
    const float* __restrict__ partials, float* __restrict__ meanw,
    signed char* __restrict__ q1, signed char* __restrict__ q2) {
  const int y = blockIdx.y, bid = blockIdx.x, t = threadIdx.x;
  const int lane = t & 63, wv = t >> 6;

  double d = 0.0;
  #pragma unroll
  for (int j = 0; j < 8; j++) d += (double)partials[y * 2048 + t + j * 256];
  #pragma unroll
  for (int off = 32; off; off >>= 1) d += __shfl_down(d, off, 64);
  __shared__ double smd[4];
  if (lane == 0) smd[wv] = d;
  __syncthreads();
  double sum = smd[0] + smd[1] + smd[2] + smd[3];
  float mean = fmaxf((float)(sum * (1.0 / (double)WCOUNT)), EPSF);
  if (bid == 0 && t == 0) meanw[y] = mean;
  float sc = 1.0f / mean;

  const float4* w4 = (const float4*)(y ? w2 : w1);
  int* q4 = (int*)(y ? q2 : q1);
  const long long base = (long long)bid * 2048;
  float4 u[8];
  #pragma unroll
  for (int k = 0; k < 8; k++) u[k] = w4[base + t + k * 256];
  #pragma unroll
  for (int k = 0; k < 8; k++)
    q4[base + t + k * 256] = pack4(u[k].x, u[k].y, u[k].z, u[k].w, sc, -1.f, 1.f);
}

// ---------------------------------------------------------------- act quant x (wave = row)

__global__ __launch_bounds__(256) void quant_x_kernel(
    const float* __restrict__ x, signed char* __restrict__ xq,
    float* __restrict__ ascale) {
  int lane = threadIdx.x & 63, wv = threadIdx.x >> 6;
  int row = blockIdx.x * 4 + wv;
  const float4* xr = (const float4*)(x + (size_t)row * DD);
  float4 v[8];
  #pragma unroll
  for (int j = 0; j < 8; j++) v[j] = xr[lane + j * 64];
  float m = 0.f;
  #pragma unroll
  for (int j = 0; j < 8; j++) m = fmaxf(m, abs4(v[j]));
  #pragma unroll
  for (int off = 32; off; off >>= 1) m = fmaxf(m, __shfl_down(m, off, 64));
  m = __shfl(m, 0, 64);
  float am = fmaxf(m, EPSF);
  float scale = 127.0f / am;
  int* out = (int*)(xq + (size_t)row * DD);
  #pragma unroll
  for (int j = 0; j < 8; j++)
    out[lane + j * 64] = pack4(v[j].x, v[j].y, v[j].z, v[j].w, scale, -128.f, 127.f);
  if (lane == 0) ascale[row] = am / 127.0f;
}

// ---------------------------------------------------------------- act quant h (int16 in)

__global__ __launch_bounds__(256) void quant_h_kernel(
    const short* __restrict__ h, signed char* __restrict__ hq,
    float* __restrict__ a2, const float* __restrict__ a1,
    const float* __restrict__ meanw) {
  int row = blockIdx.x;
  int t = threadIdx.x;
  const v8s* hr = (const v8s*)(h + (size_t)row * HH);
  v8s v[4];
  #pragma unroll
  for (int i = 0; i < 4; i++) v[i] = hr[t + i * 256];
  int mx = 0;
  #pragma unroll
  for (int i = 0; i < 4; i++)
    #pragma unroll
    for (int j = 0; j < 8; j++) mx = max(mx, (int)v[i][j]);
  int bmx = blockMaxI256(mx);
  float f = a1[row] * meanw[0];      // per-row dequant factor (exact ref path)
  float maxh = (float)bmx * f;       // == max_j fl(r_j*f): fl monotone, f>=0
  float am = fmaxf(maxh, EPSF);
  float scale = 127.0f / am;
  int* out = (int*)(hq + (size_t)row * HH);
  #pragma unroll
  for (int i = 0; i < 4; i++) {
    out[(t + i * 256) * 2] =
        pack4((float)v[i][0] * f, (float)v[i][1] * f, (float)v[i][2] * f,
              (float)v[i][3] * f, scale, -128.f, 127.f);
    out[(t + i * 256) * 2 + 1] =
        pack4((float)v[i][4] * f, (float)v[i][5] * f, (float)v[i][6] * f,
              (float)v[i][7] * f, scale, -128.f, 127.f);
  }
  if (t == 0) a2[row] = am / 127.0f;
}

// ---------------------------------------------------------------- GEMM1: 8-phase 256x256 int8
// m201-style schedule ported to int8.  512 thr / 8 waves (2Mx4N), wave tile
// 128x64 (MI=8, NJ=4), BK=64, ring-4 LDS (128 KB).  Per K-tile: TWO phases,
// each {frag ds_reads + 1 half-tile stage issue -> bare s_barrier ->
// setprio(1) + 16 MFMA cluster + setprio(0) -> s_barrier(+lgkmcnt(0))}.
// Counted vmcnt(8) once per K-tile (3 tiles in flight, never drained to 0 in
// steady state).  lgkmcnt(0) folded into every post-MFMA fence so no wave can
// pass the slot-freeing barrier with ds_reads still in flight (rule-18 sink
// hazard).  LDS swizzle: 16B chunk c of row r holds global chunk
// c ^ ((r>>1)&3) (0 conflicts, verified R1); applied via pre-swizzled global
// source + swizzled ds_read, linear LDS dest (global_load_lds rule).

__global__ __launch_bounds__(512, 2) void gemm1_8ph(
    const signed char* __restrict__ A, const signed char* __restrict__ B,
    short* __restrict__ C, int M, int N, int K) {
  __shared__ __align__(16) signed char As[4][256 * 64];
  __shared__ __align__(16) signed char Bs[4][256 * 64];

  const int t = threadIdx.x;
  const int lane = t & 63, wv = t >> 6;
  const int wm = wv >> 2, wn = wv & 3;   // 2x4 wave grid
  const int q = lane >> 4;

  int mt, nt;
  swizzle_tiles(mt, nt);
  const int m0 = mt * 256, n0 = nt * 256;

  // staging: per-lane pre-swizzled global source; wave-uniform LDS base
  const signed char* aS[2];
  const signed char* bS[2];
  int dOf[2];
  #pragma unroll
  for (int j = 0; j < 2; j++) {
    int n = t + j * 512;                 // 16B chunk index in slot [0,1024)
    int r = n >> 2;
    int cg = (n & 3) ^ ((r >> 1) & 3);
    aS[j] = A + (size_t)(m0 + r) * K + cg * 16;
    bS[j] = B + (size_t)(n0 + r) * K + cg * 16;
    dOf[j] = (wv * 64 + j * 512) * 16;   // wave-uniform base (+lane*16 by HW)
  }

  // fragment LDS byte offsets
  int aOff[8], bOff[4];
  #pragma unroll
  for (int i = 0; i < 8; i++) {
    int r = wm * 128 + i * 16 + (lane & 15);
    aOff[i] = r * 64 + ((q ^ ((r >> 1) & 3)) << 4);
  }
  #pragma unroll
  for (int j = 0; j < 4; j++) {
    int r = wn * 64 + j * 16 + (lane & 15);
    bOff[j] = r * 64 + ((q ^ ((r >> 1) & 3)) << 4);
  }

  v4i acc[8][4];
  #pragma unroll
  for (int i = 0; i < 8; i++)
    #pragma unroll
    for (int j = 0; j < 4; j++) {
      v4i z = {0, 0, 0, 0};
      acc[i][j] = z;
    }

  auto stageHalf = [&](int kt, int sl, int j) {
    async_copy16(aS[j] + (size_t)kt * 64, &As[sl][dOf[j]]);
    async_copy16(bS[j] + (size_t)kt * 64, &Bs[sl][dOf[j]]);
  };

  const int NTK = K >> 6;  // 32

  // prologue: stage tiles 0,1,2 (12 loads); wait to 8 -> tile 0 landed
  #pragma unroll
  for (int p = 0; p < 3; p++) {
    stageHalf(p, p, 0);
    stageHalf(p, p, 1);
  }
  asm volatile("s_waitcnt vmcnt(8)\n\ts_barrier" ::: "memory");

  v4i af[4], af2[4], bf[4];
  for (int kt = 0; kt < NTK; ++kt) {
    const int sl = kt & 3;
    const signed char* as_ = As[sl];
    const signed char* bs_ = Bs[sl];
    const bool st = (kt + 3 < NTK);

    // ---- phase 0: bf[0:4] + af[0:4] reads, stage half 0 of tile kt+3
    #pragma unroll
    for (int j = 0; j < 4; j++) bf[j] = *(const v4i*)(bs_ + bOff[j]);
    #pragma unroll
    for (int i = 0; i < 4; i++) af[i] = *(const v4i*)(as_ + aOff[i]);
    if (st) stageHalf(kt + 3, (kt + 3) & 3, 0);
    asm volatile("s_barrier" ::: "memory");           // reads stay in flight
    __builtin_amdgcn_s_setprio(1);
    #pragma unroll
    for (int i = 0; i < 4; i++)
      #pragma unroll
      for (int j = 0; j < 4; j++)
        acc[i][j] =
            __builtin_amdgcn_mfma_i32_16x16x64_i8(af[i], bf[j], acc[i][j], 0, 0, 0);
    __builtin_amdgcn_s_setprio(0);
    // post-MFMA fence: lgkm drained (free if MFMAs stayed clustered)
    asm volatile("s_waitcnt lgkmcnt(0)\n\ts_barrier" ::: "memory");

    // ---- phase 1: af2[0:4] reads (bf reused), stage half 1 of tile kt+3
    #pragma unroll
    for (int i = 0; i < 4; i++) af2[i] = *(const v4i*)(as_ + aOff[i + 4]);
    if (st) stageHalf(kt + 3, (kt + 3) & 3, 1);
    asm volatile("s_barrier" ::: "memory");
    __builtin_amdgcn_s_setprio(1);
    #pragma unroll
    for (int i = 0; i < 4; i++)
      #pragma unroll
      for (int j = 0; j < 4; j++)
        acc[i + 4][j] =
            __builtin_amdgcn_mfma_i32_16x16x64_i8(af2[i], bf[j], acc[i + 4][j], 0, 0, 0);
    __builtin_amdgcn_s_setprio(0);
    // end-of-K-tile fence: counted vmcnt (tile kt+1 lands; 2 tiles stay in
    // flight in steady state), lgkmcnt(0) for the slot-free guarantee
    if (kt < NTK - 3)
      asm volatile("s_waitcnt vmcnt(8) lgkmcnt(0)\n\ts_barrier" ::: "memory");
    else if (kt == NTK - 3)
      asm volatile("s_waitcnt vmcnt(4) lgkmcnt(0)\n\ts_barrier" ::: "memory");
    else if (kt == NTK - 2)
      asm volatile("s_waitcnt vmcnt(0) lgkmcnt(0)\n\ts_barrier" ::: "memory");
    else
      asm volatile("s_waitcnt lgkmcnt(0)" ::: "memory");
  }

  // epilogue: relu -> int16 (same mapping as verified R0/R1)
  #pragma unroll
  for (int i = 0; i < 8; i++) {
    int mBase = m0 + wm * 128 + i * 16 + q * 4;
    #pragma unroll
    for (int e = 0; e < 4; e++) {
      #pragma unroll
      for (int j = 0; j < 4; j++) {
        int n = n0 + wn * 64 + j * 16 + (lane & 15);
        int r = acc[i][j][e];
        r = r < 0 ? 0 : (r > 32767 ? 32767 : r);
        C[(size_t)(mBase + e) * N + n] = (short)r;
      }
    }
  }
}

// ---------------------------------------------------------------- GEMM2: round-0 structure (frozen, 91 us known-good)
// 128x128 tile, 4 waves 2x2, BK=256, global_load_lds w16, XOR 16B-chunk
// swizzle (0 conflicts), drain barriers, 2 blocks/CU.  MODE 0: scaled fp32.

template <int MODE, int BK>
__global__ __launch_bounds__(256) void gemm_i8_kernel(
    const signed char* __restrict__ A, const signed char* __restrict__ B,
    void* __restrict__ Cout, const float* __restrict__ ascale,
    const float* __restrict__ wmean_p, int M, int N, int K) {
  constexpr int CH = BK / 16;
  constexpr int SEGROWS = 1024 / BK;
  constexpr int SPW = BK / 32;
  __shared__ signed char As[128 * BK];
  __shared__ signed char Bs[128 * BK];

  const int t = threadIdx.x;
  const int lane = t & 63, wv = t >> 6;
  const int wm = wv >> 1, wn = wv & 1;
  int mt, nt;
  swizzle_tiles(mt, nt);
  const int m0 = mt * 128, n0 = nt * 128;
  const int q = lane >> 4;

  const signed char* aSrc[SPW];
  const signed char* bSrc[SPW];
  #pragma unroll
  for (int i = 0; i < SPW; i++) {
    int seg = wv * SPW + i;
    int r = seg * SEGROWS + lane / CH;
    int c = (lane % CH) ^ (r & (CH - 1));
    aSrc[i] = A + (size_t)(m0 + r) * K + c * 16;
    bSrc[i] = B + (size_t)(n0 + r) * K + c * 16;
  }

  v4i acc[4][4];
  #pragma unroll
  for (int i = 0; i < 4; i++)
    #pragma unroll
    for (int j = 0; j < 4; j++) {
      v4i z = {0, 0, 0, 0};
      acc[i][j] = z;
    }

  int rowA[4], rowB[4];
  #pragma unroll
  for (int i = 0; i < 4; i++) {
    rowA[i] = wm * 64 + i * 16 + (lane & 15);
    rowB[i] = wn * 64 + i * 16 + (lane & 15);
  }

  for (int k0 = 0; k0 < K; k0 += BK) {
    #pragma unroll
    for (int i = 0; i < SPW; i++) {
      async_copy16(aSrc[i] + k0, &As[(wv * SPW + i) * 1024]);
      async_copy16(bSrc[i] + k0, &Bs[(wv * SPW + i) * 1024]);
    }
    __syncthreads();
    #pragma unroll
    for (int kc = 0; kc < CH / 4; kc++) {
      v4i af[4], bf[4];
      #pragma unroll
      for (int i = 0; i < 4; i++) {
        int ca = (kc * 4 + q) ^ (rowA[i] & (CH - 1));
        af[i] = *(const v4i*)(As + rowA[i] * BK + ca * 16);
        int cb = (kc * 4 + q) ^ (rowB[i] & (CH - 1));
        bf[i] = *(const v4i*)(Bs + rowB[i] * BK + cb * 16);
      }
      #pragma unroll
      for (int i = 0; i < 4; i++)
        #pragma unroll
        for (int j = 0; j < 4; j++)
          acc[i][j] = __builtin_amdgcn_mfma_i32_16x16x64_i8(af[i], bf[j], acc[i][j], 0, 0, 0);
    }
    __syncthreads();
  }

  if constexpr (MODE == 1) {
    short* C = (short*)Cout;
    #pragma unroll
    for (int i = 0; i < 4; i++) {
      int mBase = m0 + wm * 64 + i * 16 + q * 4;
      #pragma unroll
      for (int e = 0; e < 4; e++) {
        #pragma unroll
        for (int j = 0; j < 4; j++) {
          int n = n0 + wn * 64 + j * 16 + (lane & 15);
          int r = acc[i][j][e];
          r = r < 0 ? 0 : (r > 32767 ? 32767 : r);
          C[(size_t)(mBase + e) * N + n] = (short)r;
        }
      }
    }
  } else {
    float* C = (float*)Cout;
    float wmean = wmean_p[0];
    #pragma unroll
    for (int i = 0; i < 4; i++) {
      int mBase = m0 + wm * 64 + i * 16 + q * 4;
      #pragma unroll
      for (int e = 0; e < 4; e++) {
        float f = ascale[mBase + e] * wmean;
        #pragma unroll
        for (int j = 0; j < 4; j++) {
          int n = n0 + wn * 64 + j * 16 + (lane & 15);
          C[(size_t)(mBase + e) * N + n] = (float)acc[i][j][e] * f;
        }
      }
    }
  }
}

// ---------------------------------------------------------------- launch

extern "C" void kernel_launch(void* const* d_in, const int* in_sizes, int n_in,
                              void* d_out, int out_size, void* d_ws, size_t ws_size,
                              hipStream_t stream) {
  const float* x  = (const float*)d_in[0];
  const float* w1 = (const float*)d_in[1];
  const float* w2 = (const float*)d_in[2];
  float* out = (float*)d_out;

  char* ws = (char*)d_ws;
  float* meanw = (float*)ws;                                // 2 f32
  float* partials = (float*)(ws + 1024);                    // 4096 f32 (16 KB)
  float* a1 = (float*)(ws + 20480);                         // 4096 f32
  float* a2 = (float*)(ws + 40960);                         // 4096 f32
  signed char* w1q = (signed char*)(ws + 65536);            // 16 MB
  signed char* w2q = w1q + (size_t)WCOUNT;                  // 16 MB
  signed char* xq  = w2q + (size_t)WCOUNT;                  // 8 MB
  signed char* hq  = xq + (size_t)MROWS * DD;               // 32 MB
  short* h16 = (short*)(hq + (size_t)MROWS * HH);           // 64 MB int16

  abs_sum_kernel<<<dim3(2048, 2), 256, 0, stream>>>(w1, w2, partials);
  quant_w_kernel<<<dim3(2048, 2), 256, 0, stream>>>(w1, w2, partials, meanw, w1q, w2q);
  quant_x_kernel<<<MROWS / 4, 256, 0, stream>>>(x, xq, a1);
  // GEMM1: M=4096, N=8192, K=2048 — 256x256 8-phase, relu->int16
  gemm1_8ph<<<dim3(HH / 256, MROWS / 256), 512, 0, stream>>>(
      xq, w1q, h16, MROWS, HH, DD);
  quant_h_kernel<<<MROWS, 256, 0, stream>>>(h16, hq, a2, a1, meanw);
  // GEMM2: M=4096, N=2048, K=8192 — round-0 kernel, BK=256, scaled fp32
  gemm_i8_kernel<0, 256><<<dim3(DD / 128, MROWS / 128), 256, 0, stream>>>(
      hq, w2q, out, a2, &meanw[1], MROWS, DD, HH);
}

// Round 3
// 373.638 us; speedup vs baseline: 1.1165x; 1.0028x over previous
//
#include <hip/hip_runtime.h>
#include <hip/hip_bf16.h>

#define EPSF 1e-5f

typedef int v4i __attribute__((ext_vector_type(4)));
typedef int v16i __attribute__((ext_vector_type(16)));
typedef short v8s __attribute__((ext_vector_type(8)));

static constexpr int BB = 4, TT = 1024, DD = 2048, HH = 8192;
static constexpr int MROWS = BB * TT;                   // 4096
static constexpr long long WCOUNT = (long long)DD * HH; // 2^24 per weight

// ---------------------------------------------------------------- helpers

__device__ __forceinline__ void async_copy16(const void* g, void* l) {
  __builtin_amdgcn_global_load_lds(
      (const __attribute__((address_space(1))) unsigned int*)g,
      (__attribute__((address_space(3))) unsigned int*)l,
      16, 0, 0);
}

__device__ __forceinline__ int pack4(float a, float b, float c, float d,
                                     float scale, float lo, float hi) {
  int ia = (int)fminf(fmaxf(rintf(a * scale), lo), hi);
  int ib = (int)fminf(fmaxf(rintf(b * scale), lo), hi);
  int ic = (int)fminf(fmaxf(rintf(c * scale), lo), hi);
  int id = (int)fminf(fmaxf(rintf(d * scale), lo), hi);
  return (ia & 0xff) | ((ib & 0xff) << 8) | ((ic & 0xff) << 16) | ((id & 0xff) << 24);
}

__device__ __forceinline__ float abs4(float4 v) {
  return fmaxf(fmaxf(fabsf(v.x), fabsf(v.y)), fmaxf(fabsf(v.z), fabsf(v.w)));
}

__device__ __forceinline__ int blockMaxI256(int v) {
  #pragma unroll
  for (int off = 32; off; off >>= 1) v = max(v, __shfl_down(v, off, 64));
  __shared__ int sm[4];
  int lane = threadIdx.x & 63, wv = threadIdx.x >> 6;
  if (lane == 0) sm[wv] = v;
  __syncthreads();
  return max(max(sm[0], sm[1]), max(sm[2], sm[3]));
}

// XCD-aware tile swizzle: id%8 class (heuristic XCD) owns a contiguous patch.
__device__ __forceinline__ void swizzle_tiles(int& mt, int& nt) {
  int Mt = gridDim.y, Nt = gridDim.x;
  int id = blockIdx.y * Nt + blockIdx.x;
  int c = id & 7, k = id >> 3;
  int pm = (Mt >= Nt) ? 4 : 2;
  int PM = Mt / pm, PN = Nt / (8 / pm);
  int pr = c % pm, pc = c / pm;
  mt = pr * PM + (k % PM);
  nt = pc * PN + (k / PM);
}

// ---------------------------------------------------------------- prep: |w| partial sums + act-quant x (fused, independent work)
// blocks [0,4096): weight abs-sum partials (y = bid>>11, extent = bid&2047).
// blocks [4096,5120): x act-quant, wave = row (4 rows/block).

__global__ __launch_bounds__(256) void prep_kernel(
    const float* __restrict__ w1, const float* __restrict__ w2,
    const float* __restrict__ x, float* __restrict__ partials,
    signed char* __restrict__ xq, float* __restrict__ ascale) {
  __shared__ float sm[4];
  const int bid = blockIdx.x, t = threadIdx.x;
  const int lane = t & 63, wv = t >> 6;

  if (bid < 4096) {
    const int y = bid >> 11, b = bid & 2047;
    const float4* w4 = (const float4*)(y ? w2 : w1);
    const long long base = (long long)b * 2048;
    float4 u[8];
    #pragma unroll
    for (int k = 0; k < 8; k++) u[k] = w4[base + t + k * 256];
    float s = 0.f;
    #pragma unroll
    for (int k = 0; k < 8; k++)
      s += fabsf(u[k].x) + fabsf(u[k].y) + fabsf(u[k].z) + fabsf(u[k].w);
    #pragma unroll
    for (int off = 32; off; off >>= 1) s += __shfl_down(s, off, 64);
    if (lane == 0) sm[wv] = s;
    __syncthreads();
    if (t == 0) partials[y * 2048 + b] = sm[0] + sm[1] + sm[2] + sm[3];
  } else {
    int row = (bid - 4096) * 4 + wv;
    const float4* xr = (const float4*)(x + (size_t)row * DD);
    float4 v[8];
    #pragma unroll
    for (int j = 0; j < 8; j++) v[j] = xr[lane + j * 64];
    float m = 0.f;
    #pragma unroll
    for (int j = 0; j < 8; j++) m = fmaxf(m, abs4(v[j]));
    #pragma unroll
    for (int off = 32; off; off >>= 1) m = fmaxf(m, __shfl_down(m, off, 64));
    m = __shfl(m, 0, 64);
    float am = fmaxf(m, EPSF);
    float scale = 127.0f / am;
    int* out = (int*)(xq + (size_t)row * DD);
    #pragma unroll
    for (int j = 0; j < 8; j++)
      out[lane + j * 64] = pack4(v[j].x, v[j].y, v[j].z, v[j].w, scale, -128.f, 127.f);
    if (lane == 0) ascale[row] = am / 127.0f;
  }
}

// ---------------------------------------------------------------- ternary quant
// Every block re-reduces the 2048 partials with an IDENTICAL tree
// (deterministic, ~8KB L2-hit reads), then quantizes its 32 KB extent.

__global__ __launch_bounds__(256) void quant_w_kernel(
    const float* __restrict__ w1, const float* __restrict__ w2,
    const float* __restrict__ partials, float* __restrict__ meanw,
    signed char* __restrict__ q1, signed char* __restrict__ q2) {
  const int y = blockIdx.y, bid = blockIdx.x, t = threadIdx.x;
  const int lane = t & 63, wv = t >> 6;

  double d = 0.0;
  #pragma unroll
  for (int j = 0; j < 8; j++) d += (double)partials[y * 2048 + t + j * 256];
  #pragma unroll
  for (int off = 32; off; off >>= 1) d += __shfl_down(d, off, 64);
  __shared__ double smd[4];
  if (lane == 0) smd[wv] = d;
  __syncthreads();
  double sum = smd[0] + smd[1] + smd[2] + smd[3];
  float mean = fmaxf((float)(sum * (1.0 / (double)WCOUNT)), EPSF);
  if (bid == 0 && t == 0) meanw[y] = mean;
  float sc = 1.0f / mean;

  const float4* w4 = (const float4*)(y ? w2 : w1);
  int* q4 = (int*)(y ? q2 : q1);
  const long long base = (long long)bid * 2048;
  float4 u[8];
  #pragma unroll
  for (int k = 0; k < 8; k++) u[k] = w4[base + t + k * 256];
  #pragma unroll
  for (int k = 0; k < 8; k++)
    q4[base + t + k * 256] = pack4(u[k].x, u[k].y, u[k].z, u[k].w, sc, -1.f, 1.f);
}

// ---------------------------------------------------------------- act quant h (int16 in, int2 packed stores)

__global__ __launch_bounds__(256) void quant_h_kernel(
    const short* __restrict__ h, signed char* __restrict__ hq,
    float* __restrict__ a2, const float* __restrict__ a1,
    const float* __restrict__ meanw) {
  int row = blockIdx.x;
  int t = threadIdx.x;
  const v8s* hr = (const v8s*)(h + (size_t)row * HH);
  v8s v[4];
  #pragma unroll
  for (int i = 0; i < 4; i++) v[i] = hr[t + i * 256];
  int mx = 0;
  #pragma unroll
  for (int i = 0; i < 4; i++)
    #pragma unroll
    for (int j = 0; j < 8; j++) mx = max(mx, (int)v[i][j]);
  int bmx = blockMaxI256(mx);
  float f = a1[row] * meanw[0];      // per-row dequant factor (exact ref path)
  float maxh = (float)bmx * f;       // == max_j fl(r_j*f): fl monotone, f>=0
  float am = fmaxf(maxh, EPSF);
  float scale = 127.0f / am;
  int2* out = (int2*)(hq + (size_t)row * HH);
  #pragma unroll
  for (int i = 0; i < 4; i++) {
    int p0 = pack4((float)v[i][0] * f, (float)v[i][1] * f, (float)v[i][2] * f,
                   (float)v[i][3] * f, scale, -128.f, 127.f);
    int p1 = pack4((float)v[i][4] * f, (float)v[i][5] * f, (float)v[i][6] * f,
                   (float)v[i][7] * f, scale, -128.f, 127.f);
    out[t + i * 256] = int2{p0, p1};
  }
  if (t == 0) a2[row] = am / 127.0f;
}

// ---------------------------------------------------------------- int8 GEMM (round-0 structure, 32x32x32 fragments)
// C[M][N] = sum_k A[M][K]*B[N][K], both operands LDS-staged via
// global_load_lds w16, XOR 16B-chunk swizzle (LDS slot s of row r holds
// global chunk s^(r&(CH-1)); read pattern gives <=2-way bank aliasing, free
// per m136).  128x128 tile, 4 waves 2x2, wave 64x64 via 2x2
// mfma_i32_32x32x32_i8 (half the MFMA instr count of 16x16x64 at the same
// OPS; 32x32 i8 pipe measured 11.7% faster, m55).  A/B frag: lane l -> row
// l&31, 16B K-half l>>5.  C/D: col=lane&31, row=(reg&3)+8*(reg>>2)+
// 4*(lane>>5) (m74/m101).  MODE 1: relu -> int16 store. MODE 0: scaled fp32.

template <int MODE, int BK>
__global__ __launch_bounds__(256) void gemm_i8_kernel(
    const signed char* __restrict__ A, const signed char* __restrict__ B,
    void* __restrict__ Cout, const float* __restrict__ ascale,
    const float* __restrict__ wmean_p, int M, int N, int K) {
  constexpr int CH = BK / 16;
  constexpr int SEGROWS = 1024 / BK;
  constexpr int SPW = BK / 32;
  __shared__ signed char As[128 * BK];
  __shared__ signed char Bs[128 * BK];

  const int t = threadIdx.x;
  const int lane = t & 63, wv = t >> 6;
  const int wm = wv >> 1, wn = wv & 1;
  int mt, nt;
  swizzle_tiles(mt, nt);
  const int m0 = mt * 128, n0 = nt * 128;
  const int hf = lane >> 5;            // K-half for 32x32 frags

  const signed char* aSrc[SPW];
  const signed char* bSrc[SPW];
  #pragma unroll
  for (int i = 0; i < SPW; i++) {
    int seg = wv * SPW + i;
    int r = seg * SEGROWS + lane / CH;
    int c = (lane % CH) ^ (r & (CH - 1));
    aSrc[i] = A + (size_t)(m0 + r) * K + c * 16;
    bSrc[i] = B + (size_t)(n0 + r) * K + c * 16;
  }

  v16i acc[2][2];
  #pragma unroll
  for (int i = 0; i < 2; i++)
    #pragma unroll
    for (int j = 0; j < 2; j++) {
      v16i z = {0, 0, 0, 0, 0, 0, 0, 0, 0, 0, 0, 0, 0, 0, 0, 0};
      acc[i][j] = z;
    }

  int rowA[2], rowB[2];
  #pragma unroll
  for (int i = 0; i < 2; i++) {
    rowA[i] = wm * 64 + i * 32 + (lane & 31);
    rowB[i] = wn * 64 + i * 32 + (lane & 31);
  }

  for (int k0 = 0; k0 < K; k0 += BK) {
    #pragma unroll
    for (int i = 0; i < SPW; i++) {
      async_copy16(aSrc[i] + k0, &As[(wv * SPW + i) * 1024]);
      async_copy16(bSrc[i] + k0, &Bs[(wv * SPW + i) * 1024]);
    }
    __syncthreads();
    #pragma unroll
    for (int ks = 0; ks < BK / 32; ks++) {
      v4i af[2], bf[2];
      #pragma unroll
      for (int i = 0; i < 2; i++) {
        int ca = (ks * 2 + hf) ^ (rowA[i] & (CH - 1));
        af[i] = *(const v4i*)(As + rowA[i] * BK + ca * 16);
        int cb = (ks * 2 + hf) ^ (rowB[i] & (CH - 1));
        bf[i] = *(const v4i*)(Bs + rowB[i] * BK + cb * 16);
      }
      #pragma unroll
      for (int i = 0; i < 2; i++)
        #pragma unroll
        for (int j = 0; j < 2; j++)
          acc[i][j] = __builtin_amdgcn_mfma_i32_32x32x32_i8(af[i], bf[j], acc[i][j], 0, 0, 0);
    }
    __syncthreads();
  }

  if constexpr (MODE == 1) {
    short* C = (short*)Cout;
    #pragma unroll
    for (int i = 0; i < 2; i++) {
      #pragma unroll
      for (int e = 0; e < 16; e++) {
        int m = m0 + wm * 64 + i * 32 + (e & 3) + 8 * (e >> 2) + 4 * hf;
        #pragma unroll
        for (int j = 0; j < 2; j++) {
          int n = n0 + wn * 64 + j * 32 + (lane & 31);
          int r = acc[i][j][e];
          r = r < 0 ? 0 : (r > 32767 ? 32767 : r);
          C[(size_t)m * N + n] = (short)r;
        }
      }
    }
  } else {
    float* C = (float*)Cout;
    float wmean = wmean_p[0];
    #pragma unroll
    for (int i = 0; i < 2; i++) {
      #pragma unroll
      for (int e = 0; e < 16; e++) {
        int m = m0 + wm * 64 + i * 32 + (e & 3) + 8 * (e >> 2) + 4 * hf;
        float f = ascale[m] * wmean;
        #pragma unroll
        for (int j = 0; j < 2; j++) {
          int n = n0 + wn * 64 + j * 32 + (lane & 31);
          C[(size_t)m * N + n] = (float)acc[i][j][e] * f;
        }
      }
    }
  }
}

// ---------------------------------------------------------------- launch

extern "C" void kernel_launch(void* const* d_in, const int* in_sizes, int n_in,
                              void* d_out, int out_size, void* d_ws, size_t ws_size,
                              hipStream_t stream) {
  const float* x  = (const float*)d_in[0];
  const float* w1 = (const float*)d_in[1];
  const float* w2 = (const float*)d_in[2];
  float* out = (float*)d_out;

  char* ws = (char*)d_ws;
  float* meanw = (float*)ws;                                // 2 f32
  float* partials = (float*)(ws + 1024);                    // 4096 f32 (16 KB)
  float* a1 = (float*)(ws + 20480);                         // 4096 f32
  float* a2 = (float*)(ws + 40960);                         // 4096 f32
  signed char* w1q = (signed char*)(ws + 65536);            // 16 MB
  signed char* w2q = w1q + (size_t)WCOUNT;                  // 16 MB
  signed char* xq  = w2q + (size_t)WCOUNT;                  // 8 MB
  signed char* hq  = xq + (size_t)MROWS * DD;               // 32 MB
  short* h16 = (short*)(hq + (size_t)MROWS * HH);           // 64 MB int16

  // prep: weight |.| partials (4096 blocks) + x act-quant (1024 blocks)
  prep_kernel<<<5120, 256, 0, stream>>>(w1, w2, x, partials, xq, a1);
  quant_w_kernel<<<dim3(2048, 2), 256, 0, stream>>>(w1, w2, partials, meanw, w1q, w2q);
  // GEMM1: M=4096, N=8192, K=2048 — BK=128, relu->int16
  gemm_i8_kernel<1, 128><<<dim3(HH / 128, MROWS / 128), 256, 0, stream>>>(
      xq, w1q, h16, nullptr, meanw, MROWS, HH, DD);
  quant_h_kernel<<<MROWS, 256, 0, stream>>>(h16, hq, a2, a1, meanw);
  // GEMM2: M=4096, N=2048, K=8192 — BK=256, scaled fp32
  gemm_i8_kernel<0, 256><<<dim3(DD / 128, MROWS / 128), 256, 0, stream>>>(
      hq, w2q, out, a2, &meanw[1], MROWS, DD, HH);
}